// Round 7
// baseline (215.599 us; speedup 1.0000x reference)
//
#include <hip/hip_runtime.h>
#include <hip/hip_bf16.h>

// GPT2 attention: B=8, T=1024, D=768, H=12, hd=64. fp32 in/out, bf16 MFMA compute.
#define B_ 8
#define T_ 1024
#define D_ 768
#define NH 12
#define HD 64

typedef __bf16 bf16x8 __attribute__((ext_vector_type(8)));
typedef __bf16 bf16x4 __attribute__((ext_vector_type(4)));
typedef float f32x4 __attribute__((ext_vector_type(4)));
typedef short s16x4 __attribute__((ext_vector_type(4)));

// exp2 on the device: v_exp_f32 is 2^x. (__exp2f collides with a glibc
// math.h reserved name — round-5 lesson; use the amdgcn builtin directly.)
__device__ __forceinline__ float fast_exp2(float x) {
  return __builtin_amdgcn_exp2f(x);
}

__device__ __forceinline__ f32x4 mfma32(bf16x8 a, bf16x8 b, f32x4 c) {
  return __builtin_amdgcn_mfma_f32_16x16x32_bf16(a, b, c, 0, 0, 0);
}

// v_mfma_f32_16x16x16_bf16 via the gfx90a-lineage builtin (round-3 lesson:
// no __has_builtin guard — host pass misreports aux-target builtins).
__device__ __forceinline__ f32x4 mfma16(bf16x4 a, bf16x4 b, f32x4 c) {
  union U { bf16x4 h; s16x4 s; };
  U ua; ua.h = a;
  U ub; ub.h = b;
  return __builtin_amdgcn_mfma_f32_16x16x16bf16_1k(ua.s, ub.s, c, 0, 0, 0);
}

// ---------------- x (fp32) -> bf16 ----------------
__global__ void xconv_kernel(const float* __restrict__ x, __bf16* __restrict__ xb, int n8) {
  int i = blockIdx.x * 256 + threadIdx.x;
  if (i >= n8) return;
  const float4* xf = (const float4*)x;
  float4 a = xf[i * 2], b = xf[i * 2 + 1];
  bf16x8 v;
  v[0] = (__bf16)a.x; v[1] = (__bf16)a.y; v[2] = (__bf16)a.z; v[3] = (__bf16)a.w;
  v[4] = (__bf16)b.x; v[5] = (__bf16)b.y; v[6] = (__bf16)b.z; v[7] = (__bf16)b.w;
  *(bf16x8*)&xb[(size_t)i * 8] = v;
}

// ---------------- W (K x N fp32) -> WT (N x K bf16) ----------------
__global__ void wtrans_kernel(const float* __restrict__ W, __bf16* __restrict__ WT, int K, int N) {
  __shared__ float tile[32][33];
  int t = threadIdx.x, col = t & 31, r0 = t >> 5;
  int n0 = blockIdx.x * 32, k0 = blockIdx.y * 32;
#pragma unroll
  for (int p = 0; p < 4; p++) {
    int r = r0 + p * 8;
    tile[r][col] = W[(size_t)(k0 + r) * N + n0 + col];
  }
  __syncthreads();
#pragma unroll
  for (int p = 0; p < 4; p++) {
    int r = r0 + p * 8;
    WT[(size_t)(n0 + r) * K + k0 + col] = (__bf16)tile[col][r];
  }
}

// ---------------- GEMM: C(MxN) = A(MxK) * BT(NxK)^T + bias ----------------
template <int EPI>
__global__ __launch_bounds__(256) void gemm_kernel(const __bf16* __restrict__ A,
                                                   const __bf16* __restrict__ BT,
                                                   const float* __restrict__ bias,
                                                   void* __restrict__ Cout,
                                                   int M, int N, int K) {
  __shared__ __align__(16) __bf16 Asm[128][72];
  __shared__ __align__(16) __bf16 Bsm[128][72];
  int tid = threadIdx.x;
  int wave = tid >> 6, lane = tid & 63, g = lane >> 4, l15 = lane & 15;
  int wr = wave >> 1, wc = wave & 1;
  int m0 = blockIdx.y * 128, n0 = blockIdx.x * 128;
  int srow = tid >> 3, sk8 = tid & 7;
  const __bf16* Ag = A + (size_t)(m0 + srow) * K + sk8 * 8;
  const __bf16* Bg = BT + (size_t)(n0 + srow) * K + sk8 * 8;

  f32x4 zz = {0.0f, 0.0f, 0.0f, 0.0f};
  f32x4 acc[4][4];
#pragma unroll
  for (int m = 0; m < 4; m++)
#pragma unroll
    for (int n = 0; n < 4; n++) acc[m][n] = zz;

  int nk = K >> 6;
  bf16x8 Av[4], Bv[4];
#pragma unroll
  for (int p = 0; p < 4; p++) {
    Av[p] = *(const bf16x8*)(Ag + (size_t)p * 32 * K);
    Bv[p] = *(const bf16x8*)(Bg + (size_t)p * 32 * K);
  }
  for (int kt = 0; kt < nk; kt++) {
    __syncthreads();
#pragma unroll
    for (int p = 0; p < 4; p++) {
      *(bf16x8*)&Asm[srow + p * 32][sk8 * 8] = Av[p];
      *(bf16x8*)&Bsm[srow + p * 32][sk8 * 8] = Bv[p];
    }
    __syncthreads();
    if (kt + 1 < nk) {
#pragma unroll
      for (int p = 0; p < 4; p++) {
        Av[p] = *(const bf16x8*)(Ag + (kt + 1) * 64 + (size_t)p * 32 * K);
        Bv[p] = *(const bf16x8*)(Bg + (kt + 1) * 64 + (size_t)p * 32 * K);
      }
    }
#pragma unroll
    for (int ks = 0; ks < 2; ks++) {
      bf16x8 af[4], bfr[4];
#pragma unroll
      for (int m = 0; m < 4; m++) af[m] = *(const bf16x8*)&Asm[wr * 64 + m * 16 + l15][ks * 32 + g * 8];
#pragma unroll
      for (int n = 0; n < 4; n++) bfr[n] = *(const bf16x8*)&Bsm[wc * 64 + n * 16 + l15][ks * 32 + g * 8];
#pragma unroll
      for (int m = 0; m < 4; m++)
#pragma unroll
        for (int n = 0; n < 4; n++)
          acc[m][n] = __builtin_amdgcn_mfma_f32_16x16x32_bf16(af[m], bfr[n], acc[m][n], 0, 0, 0);
    }
  }
#pragma unroll
  for (int n = 0; n < 4; n++) {
    int gcol = n0 + wc * 64 + n * 16 + l15;
    float bv = bias[gcol];
#pragma unroll
    for (int m = 0; m < 4; m++) {
      int grow0 = m0 + wr * 64 + m * 16 + g * 4;
#pragma unroll
      for (int r = 0; r < 4; r++) {
        float v = acc[m][n][r] + bv;
        if (EPI == 0)
          ((__bf16*)Cout)[(size_t)(grow0 + r) * N + gcol] = (__bf16)v;
        else
          ((float*)Cout)[(size_t)(grow0 + r) * N + gcol] = v;
      }
    }
  }
}

// ---------------- V from qkv -> VT [bh][d][t] bf16 ----------------
__global__ void vtrepack_kernel(const __bf16* __restrict__ qkv, __bf16* __restrict__ VT) {
  __shared__ __align__(16) __bf16 tl[64][72];
  int bh = blockIdx.y;
  int b = bh / NH, h = bh % NH;
  int t0 = blockIdx.x * 64;
  int tid = threadIdx.x;
  int tr = tid >> 3, d8 = tid & 7;
#pragma unroll
  for (int p = 0; p < 2; p++) {
    int trow = tr + p * 32;
    bf16x8 v = *(const bf16x8*)&qkv[(size_t)(b * T_ + t0 + trow) * (3 * D_) + 2 * D_ + h * HD + d8 * 8];
#pragma unroll
    for (int e = 0; e < 8; e++) tl[d8 * 8 + e][trow] = v[e];
  }
  __syncthreads();
  int t8 = tid & 7;
#pragma unroll
  for (int p = 0; p < 2; p++) {
    int d = (tid >> 3) + p * 32;
    *(bf16x8*)&VT[((size_t)bh * HD + d) * T_ + t0 + t8 * 8] = *(const bf16x8*)&tl[d][t8 * 8];
  }
}

// ---------------- causal flash attention ----------------
// Zero LDS, zero barriers. Wave = one 16-row q-tile PAIR (p, 63-p): uniform
// 33 K-steps per wave. grid(96,8) bh-major: linear id % 8 = bh % 8 -> all
// blocks of a head pin to one XCD (L2-resident K/V, r6 lesson). 768 blocks =
// 3 blocks/CU = 3 waves/SIMD (r6 had 1 — the occupancy fix this round).
// S^T = mfma32(K, Q); softmax output feeds PV in-register (S^T C/D row
// layout == mfma16 B-frag k layout). exp2 softmax with folded log2(e).
#define SCL 0.1803368801111204f  // 0.125 * log2(e)

struct KVF {
  bf16x8 kf0, kf1, kg0, kg1;
  bf16x4 va0, va1, va2, va3;
  bf16x4 vb0, vb1, vb2, vb3;
};

__global__ __launch_bounds__(256) void attn_kernel(const __bf16* __restrict__ qkv,
                                                   const __bf16* __restrict__ VT,
                                                   __bf16* __restrict__ attn_out) {
  int tid = threadIdx.x;
  int wave = tid >> 6, lane = tid & 63, g = lane >> 4, l15 = lane & 15;
  int bh = blockIdx.x;
  int b = bh / NH, h = bh % NH;
  int pair = blockIdx.y * 4 + wave;  // 0..31

  const __bf16* Kbase = qkv + (size_t)(b * T_) * (3 * D_) + D_ + h * HD;
  const __bf16* Vbase = VT + ((size_t)bh * HD + l15) * T_;
  f32x4 zz = {0.0f, 0.0f, 0.0f, 0.0f};

  auto load_kv = [&](int kt, KVF& t) {
    const __bf16* Kb = Kbase + (size_t)(kt * 32) * (3 * D_);
    t.kf0 = *(const bf16x8*)(Kb + (size_t)l15 * (3 * D_) + g * 8);
    t.kf1 = *(const bf16x8*)(Kb + (size_t)l15 * (3 * D_) + 32 + g * 8);
    t.kg0 = *(const bf16x8*)(Kb + (size_t)(16 + l15) * (3 * D_) + g * 8);
    t.kg1 = *(const bf16x8*)(Kb + (size_t)(16 + l15) * (3 * D_) + 32 + g * 8);
    const __bf16* Vb = Vbase + kt * 32 + g * 4;
    t.va0 = *(const bf16x4*)(Vb);
    t.va1 = *(const bf16x4*)(Vb + 16 * T_);
    t.va2 = *(const bf16x4*)(Vb + 32 * T_);
    t.va3 = *(const bf16x4*)(Vb + 48 * T_);
    t.vb0 = *(const bf16x4*)(Vb + 16);
    t.vb1 = *(const bf16x4*)(Vb + 16 * T_ + 16);
    t.vb2 = *(const bf16x4*)(Vb + 32 * T_ + 16);
    t.vb3 = *(const bf16x4*)(Vb + 48 * T_ + 16);
  };

  auto do_tile = [&](int tile) {
    int q0 = tile * 16;
    const __bf16* Qp = qkv + (size_t)(b * T_ + q0 + l15) * (3 * D_) + h * HD;
    bf16x8 qlo = *(const bf16x8*)(Qp + g * 8);
    bf16x8 qhi = *(const bf16x8*)(Qp + 32 + g * 8);
    f32x4 o0 = zz, o1 = zz, o2 = zz, o3 = zz;
    float m = -1e30f, l = 0.0f;
    int nkt = (tile >> 1) + 1;
    int lastmode = (tile & 1) ? 2 : 1;

    auto step = [&](const KVF& t, int kt) {
      f32x4 sA = mfma32(t.kf0, qlo, zz);
      sA = mfma32(t.kf1, qhi, sA);
      f32x4 sB = mfma32(t.kg0, qlo, zz);
      sB = mfma32(t.kg1, qhi, sB);
      int mode = (kt == nkt - 1) ? lastmode : 0;
      float v[8];
#pragma unroll
      for (int r = 0; r < 4; r++) { v[r] = sA[r] * SCL; v[4 + r] = sB[r] * SCL; }
      if (mode == 1) {
#pragma unroll
        for (int r = 0; r < 4; r++) { if (g * 4 + r > l15) v[r] = -1e30f; v[4 + r] = -1e30f; }
      } else if (mode == 2) {
#pragma unroll
        for (int r = 0; r < 4; r++) { if (g * 4 + r > l15) v[4 + r] = -1e30f; }
      }
      float mx = fmaxf(fmaxf(fmaxf(v[0], v[1]), fmaxf(v[2], v[3])),
                       fmaxf(fmaxf(v[4], v[5]), fmaxf(v[6], v[7])));
      mx = fmaxf(mx, __shfl_xor(mx, 16));
      mx = fmaxf(mx, __shfl_xor(mx, 32));
      float mnew = fmaxf(m, mx);
      float corr = fast_exp2(m - mnew);
      float p[8], sum = 0.0f;
#pragma unroll
      for (int i = 0; i < 8; i++) { p[i] = fast_exp2(v[i] - mnew); sum += p[i]; }
      sum += __shfl_xor(sum, 16);
      sum += __shfl_xor(sum, 32);
      l = l * corr + sum;
      m = mnew;
      o0 *= corr; o1 *= corr; o2 *= corr; o3 *= corr;
      bf16x4 pkA = {(__bf16)p[0], (__bf16)p[1], (__bf16)p[2], (__bf16)p[3]};
      bf16x4 pkB = {(__bf16)p[4], (__bf16)p[5], (__bf16)p[6], (__bf16)p[7]};
      o0 = mfma16(t.va0, pkA, o0); o0 = mfma16(t.vb0, pkB, o0);
      o1 = mfma16(t.va1, pkA, o1); o1 = mfma16(t.vb1, pkB, o1);
      o2 = mfma16(t.va2, pkA, o2); o2 = mfma16(t.vb2, pkB, o2);
      o3 = mfma16(t.va3, pkA, o3); o3 = mfma16(t.vb3, pkB, o3);
    };

    KVF bufA, bufB;
    load_kv(0, bufA);
    int kt = 0;
    while (kt + 2 <= nkt) {
      load_kv(kt + 1, bufB);
      step(bufA, kt);
      if (kt + 2 < nkt) load_kv(kt + 2, bufA);
      step(bufB, kt + 1);
      kt += 2;
    }
    if (kt < nkt) step(bufA, kt);

    float invl = 1.0f / l;
    __bf16* outp = attn_out + (size_t)(b * T_ + q0 + l15) * D_ + h * HD + g * 4;
    bf16x4 s0 = {(__bf16)(o0[0] * invl), (__bf16)(o0[1] * invl), (__bf16)(o0[2] * invl), (__bf16)(o0[3] * invl)};
    bf16x4 s1 = {(__bf16)(o1[0] * invl), (__bf16)(o1[1] * invl), (__bf16)(o1[2] * invl), (__bf16)(o1[3] * invl)};
    bf16x4 s2 = {(__bf16)(o2[0] * invl), (__bf16)(o2[1] * invl), (__bf16)(o2[2] * invl), (__bf16)(o2[3] * invl)};
    bf16x4 s3 = {(__bf16)(o3[0] * invl), (__bf16)(o3[1] * invl), (__bf16)(o3[2] * invl), (__bf16)(o3[3] * invl)};
    *(bf16x4*)(outp) = s0;
    *(bf16x4*)(outp + 16) = s1;
    *(bf16x4*)(outp + 32) = s2;
    *(bf16x4*)(outp + 48) = s3;
  };

  do_tile(pair);
  do_tile(63 - pair);
}

extern "C" void kernel_launch(void* const* d_in, const int* in_sizes, int n_in,
                              void* d_out, int out_size, void* d_ws, size_t ws_size,
                              hipStream_t stream) {
  (void)in_sizes; (void)n_in; (void)out_size; (void)ws_size;
  const float* x = (const float*)d_in[0];
  const float* W_attn = (const float*)d_in[1];
  const float* b_attn = (const float*)d_in[2];
  const float* W_proj = (const float*)d_in[3];
  const float* b_proj = (const float*)d_in[4];

  char* ws = (char*)d_ws;
  __bf16* xb  = (__bf16*)(ws + 0);          // 8192*768*2        = 12,582,912
  __bf16* WaT = (__bf16*)(ws + 12582912);   // 2304*768*2        =  3,538,944
  __bf16* WpT = (__bf16*)(ws + 16121856);   // 768*768*2         =  1,179,648
  __bf16* qkv = (__bf16*)(ws + 17301504);   // 8192*2304*2       = 37,748,736
  __bf16* VTb = (__bf16*)(ws + 55050240);   // 96*64*1024*2      = 12,582,912
  __bf16* att = (__bf16*)(ws + 67633152);   // 8192*768*2        = 12,582,912

  xconv_kernel<<<dim3(3072), 256, 0, stream>>>(x, xb, 786432);
  wtrans_kernel<<<dim3(72, 24), 256, 0, stream>>>(W_attn, WaT, 768, 2304);
  wtrans_kernel<<<dim3(24, 24), 256, 0, stream>>>(W_proj, WpT, 768, 768);
  gemm_kernel<0><<<dim3(18, 64), 256, 0, stream>>>(xb, WaT, b_attn, qkv, 8192, 2304, 768);
  vtrepack_kernel<<<dim3(16, 96), 256, 0, stream>>>(qkv, VTb);
  attn_kernel<<<dim3(96, 8), 256, 0, stream>>>(qkv, VTb, att);
  gemm_kernel<1><<<dim3(6, 64), 256, 0, stream>>>(att, WpT, b_proj, d_out, 8192, 768, 768);
}

// Round 8
// 195.400 us; speedup vs baseline: 1.1034x; 1.1034x over previous
//
#include <hip/hip_runtime.h>
#include <hip/hip_bf16.h>

// GPT2 attention: B=8, T=1024, D=768, H=12, hd=64. fp32 in/out, bf16 MFMA compute.
#define B_ 8
#define T_ 1024
#define D_ 768
#define NH 12
#define HD 64

typedef __bf16 bf16x8 __attribute__((ext_vector_type(8)));
typedef __bf16 bf16x4 __attribute__((ext_vector_type(4)));
typedef float f32x4 __attribute__((ext_vector_type(4)));
typedef short s16x4 __attribute__((ext_vector_type(4)));

__device__ __forceinline__ float fast_exp2(float x) {
  return __builtin_amdgcn_exp2f(x);
}

__device__ __forceinline__ f32x4 mfma32(bf16x8 a, bf16x8 b, f32x4 c) {
  return __builtin_amdgcn_mfma_f32_16x16x32_bf16(a, b, c, 0, 0, 0);
}

__device__ __forceinline__ f32x4 mfma16(bf16x4 a, bf16x4 b, f32x4 c) {
  union U { bf16x4 h; s16x4 s; };
  U ua; ua.h = a;
  U ub; ub.h = b;
  return __builtin_amdgcn_mfma_f32_16x16x16bf16_1k(ua.s, ub.s, c, 0, 0, 0);
}

// async global->LDS, 16B per lane (compiler never auto-emits this)
__device__ __forceinline__ void gload_lds16(const void* g, void* l) {
  __builtin_amdgcn_global_load_lds((const __attribute__((address_space(1))) unsigned int*)g,
                                   (__attribute__((address_space(3))) unsigned int*)l, 16, 0, 0);
}

// ---------------- x (fp32) -> bf16 ----------------
__global__ void xconv_kernel(const float* __restrict__ x, __bf16* __restrict__ xb, int n8) {
  int i = blockIdx.x * 256 + threadIdx.x;
  if (i >= n8) return;
  const float4* xf = (const float4*)x;
  float4 a = xf[i * 2], b = xf[i * 2 + 1];
  bf16x8 v;
  v[0] = (__bf16)a.x; v[1] = (__bf16)a.y; v[2] = (__bf16)a.z; v[3] = (__bf16)a.w;
  v[4] = (__bf16)b.x; v[5] = (__bf16)b.y; v[6] = (__bf16)b.z; v[7] = (__bf16)b.w;
  *(bf16x8*)&xb[(size_t)i * 8] = v;
}

// ---------------- W (K x N fp32) -> WT (N x K bf16) ----------------
__global__ void wtrans_kernel(const float* __restrict__ W, __bf16* __restrict__ WT, int K, int N) {
  __shared__ float tile[32][33];
  int t = threadIdx.x, col = t & 31, r0 = t >> 5;
  int n0 = blockIdx.x * 32, k0 = blockIdx.y * 32;
#pragma unroll
  for (int p = 0; p < 4; p++) {
    int r = r0 + p * 8;
    tile[r][col] = W[(size_t)(k0 + r) * N + n0 + col];
  }
  __syncthreads();
#pragma unroll
  for (int p = 0; p < 4; p++) {
    int r = r0 + p * 8;
    WT[(size_t)(n0 + r) * K + k0 + col] = (__bf16)tile[col][r];
  }
}

// ---------------- GEMM: C(MxN) = A(MxK) * BT(NxK)^T + bias ----------------
template <int EPI>
__global__ __launch_bounds__(256) void gemm_kernel(const __bf16* __restrict__ A,
                                                   const __bf16* __restrict__ BT,
                                                   const float* __restrict__ bias,
                                                   void* __restrict__ Cout,
                                                   int M, int N, int K) {
  __shared__ __align__(16) __bf16 Asm[128][72];
  __shared__ __align__(16) __bf16 Bsm[128][72];
  int tid = threadIdx.x;
  int wave = tid >> 6, lane = tid & 63, g = lane >> 4, l15 = lane & 15;
  int wr = wave >> 1, wc = wave & 1;
  int m0 = blockIdx.y * 128, n0 = blockIdx.x * 128;
  int srow = tid >> 3, sk8 = tid & 7;
  const __bf16* Ag = A + (size_t)(m0 + srow) * K + sk8 * 8;
  const __bf16* Bg = BT + (size_t)(n0 + srow) * K + sk8 * 8;

  f32x4 zz = {0.0f, 0.0f, 0.0f, 0.0f};
  f32x4 acc[4][4];
#pragma unroll
  for (int m = 0; m < 4; m++)
#pragma unroll
    for (int n = 0; n < 4; n++) acc[m][n] = zz;

  int nk = K >> 6;
  bf16x8 Av[4], Bv[4];
#pragma unroll
  for (int p = 0; p < 4; p++) {
    Av[p] = *(const bf16x8*)(Ag + (size_t)p * 32 * K);
    Bv[p] = *(const bf16x8*)(Bg + (size_t)p * 32 * K);
  }
  for (int kt = 0; kt < nk; kt++) {
    __syncthreads();
#pragma unroll
    for (int p = 0; p < 4; p++) {
      *(bf16x8*)&Asm[srow + p * 32][sk8 * 8] = Av[p];
      *(bf16x8*)&Bsm[srow + p * 32][sk8 * 8] = Bv[p];
    }
    __syncthreads();
    if (kt + 1 < nk) {
#pragma unroll
      for (int p = 0; p < 4; p++) {
        Av[p] = *(const bf16x8*)(Ag + (kt + 1) * 64 + (size_t)p * 32 * K);
        Bv[p] = *(const bf16x8*)(Bg + (kt + 1) * 64 + (size_t)p * 32 * K);
      }
    }
#pragma unroll
    for (int ks = 0; ks < 2; ks++) {
      bf16x8 af[4], bfr[4];
#pragma unroll
      for (int m = 0; m < 4; m++) af[m] = *(const bf16x8*)&Asm[wr * 64 + m * 16 + l15][ks * 32 + g * 8];
#pragma unroll
      for (int n = 0; n < 4; n++) bfr[n] = *(const bf16x8*)&Bsm[wc * 64 + n * 16 + l15][ks * 32 + g * 8];
#pragma unroll
      for (int m = 0; m < 4; m++)
#pragma unroll
        for (int n = 0; n < 4; n++)
          acc[m][n] = __builtin_amdgcn_mfma_f32_16x16x32_bf16(af[m], bfr[n], acc[m][n], 0, 0, 0);
    }
  }
#pragma unroll
  for (int n = 0; n < 4; n++) {
    int gcol = n0 + wc * 64 + n * 16 + l15;
    float bv = bias[gcol];
#pragma unroll
    for (int m = 0; m < 4; m++) {
      int grow0 = m0 + wr * 64 + m * 16 + g * 4;
#pragma unroll
      for (int r = 0; r < 4; r++) {
        float v = acc[m][n][r] + bv;
        if (EPI == 0)
          ((__bf16*)Cout)[(size_t)(grow0 + r) * N + gcol] = (__bf16)v;
        else
          ((float*)Cout)[(size_t)(grow0 + r) * N + gcol] = v;
      }
    }
  }
}

// ---------------- V from qkv -> VT [bh][d][t] bf16 ----------------
__global__ void vtrepack_kernel(const __bf16* __restrict__ qkv, __bf16* __restrict__ VT) {
  __shared__ __align__(16) __bf16 tl[64][72];
  int bh = blockIdx.y;
  int b = bh / NH, h = bh % NH;
  int t0 = blockIdx.x * 64;
  int tid = threadIdx.x;
  int tr = tid >> 3, d8 = tid & 7;
#pragma unroll
  for (int p = 0; p < 2; p++) {
    int trow = tr + p * 32;
    bf16x8 v = *(const bf16x8*)&qkv[(size_t)(b * T_ + t0 + trow) * (3 * D_) + 2 * D_ + h * HD + d8 * 8];
#pragma unroll
    for (int e = 0; e < 8; e++) tl[d8 * 8 + e][trow] = v[e];
  }
  __syncthreads();
  int t8 = tid & 7;
#pragma unroll
  for (int p = 0; p < 2; p++) {
    int d = (tid >> 3) + p * 32;
    *(bf16x8*)&VT[((size_t)bh * HD + d) * T_ + t0 + t8 * 8] = *(const bf16x8*)&tl[d][t8 * 8];
  }
}

// ---------------- causal flash attention ----------------
// Block = one (bh, 64-row q-block); 4 waves x 16 q-rows; KVBLK=32.
// K staged in LDS via async global_load_lds, double-buffered, SHARED by all
// 4 waves (traffic /4; latency hidden by stage-ahead + barrier) — fixes the
// r6/r7 disease (global->reg loads serialized on L2 latency at ~5-10K cy/step).
// V loaded to regs at step top, consumed after QK+softmax (~500cy hiding).
// nkt = 2qb+2 is block-uniform; heavy q-blocks dispatched first (y reversed);
// grid bh-major: id%8 = bh%8 -> head pinned to one XCD (L2-resident K/V).
// S^T = mfma32(K, Q); softmax feeds PV in-register; exp2 softmax.
#define SCL 0.1803368801111204f  // 0.125 * log2(e)

__global__ __launch_bounds__(256, 3) void attn_kernel(const __bf16* __restrict__ qkv,
                                                      const __bf16* __restrict__ VT,
                                                      __bf16* __restrict__ attn_out) {
  __shared__ __align__(16) __bf16 Ksm[2][2048];  // 2 bufs x (32 keys x 64 d), linear
  int tid = threadIdx.x;
  int wave = tid >> 6, lane = tid & 63, g = lane >> 4, l15 = lane & 15;
  int bh = blockIdx.x;
  int b = bh / NH, h = bh % NH;
  int qb = 15 - blockIdx.y;  // heavy first
  int q0w = qb * 64 + wave * 16;
  int nkt = 2 * qb + 2;  // block-uniform

  // K staging: thread tid covers key = tid>>3, 16B chunk = tid&7 (linear LDS)
  const __bf16* Ksrc0 = qkv + (size_t)(b * T_ + (tid >> 3)) * (3 * D_) + D_ + h * HD + (tid & 7) * 8;
  const __bf16* Vbase = VT + ((size_t)bh * HD + l15) * T_;
  f32x4 zz = {0.0f, 0.0f, 0.0f, 0.0f};

  // Q fragments (B-operand: col=q=l15, k=d)
  const __bf16* Qp = qkv + (size_t)(b * T_ + q0w + l15) * (3 * D_) + h * HD;
  bf16x8 qlo = *(const bf16x8*)(Qp + g * 8);
  bf16x8 qhi = *(const bf16x8*)(Qp + 32 + g * 8);

  f32x4 o0 = zz, o1 = zz, o2 = zz, o3 = zz;
  float m = -1e30f, l = 0.0f;

  // prologue: stage K tile 0
  gload_lds16(Ksrc0, &Ksm[0][tid * 8]);
  __syncthreads();

  int cur = 0;
  for (int kt = 0; kt < nkt; kt++) {
    // stage next K tile into the other buffer (async; drains at syncthreads)
    if (kt + 1 < nkt)
      gload_lds16(Ksrc0 + (size_t)((kt + 1) * 32) * (3 * D_), &Ksm[cur ^ 1][tid * 8]);

    // V for this step: issue early, consumed after QK^T+softmax
    const __bf16* Vb = Vbase + kt * 32 + g * 4;
    bf16x4 va0 = *(const bf16x4*)(Vb);
    bf16x4 va1 = *(const bf16x4*)(Vb + 16 * T_);
    bf16x4 va2 = *(const bf16x4*)(Vb + 32 * T_);
    bf16x4 va3 = *(const bf16x4*)(Vb + 48 * T_);
    bf16x4 vb0 = *(const bf16x4*)(Vb + 16);
    bf16x4 vb1 = *(const bf16x4*)(Vb + 16 * T_ + 16);
    bf16x4 vb2 = *(const bf16x4*)(Vb + 32 * T_ + 16);
    bf16x4 vb3 = *(const bf16x4*)(Vb + 48 * T_ + 16);

    // K fragments from LDS (shared across the 4 waves)
    const __bf16* Kb = &Ksm[cur][0];
    bf16x8 kf0 = *(const bf16x8*)(Kb + l15 * 64 + g * 8);
    bf16x8 kf1 = *(const bf16x8*)(Kb + l15 * 64 + 32 + g * 8);
    bf16x8 kg0 = *(const bf16x8*)(Kb + (16 + l15) * 64 + g * 8);
    bf16x8 kg1 = *(const bf16x8*)(Kb + (16 + l15) * 64 + 32 + g * 8);

    f32x4 sA = mfma32(kf0, qlo, zz);
    sA = mfma32(kf1, qhi, sA);
    f32x4 sB = mfma32(kg0, qlo, zz);
    sB = mfma32(kg1, qhi, sB);

    int key0 = kt * 32;
    float v[8];
#pragma unroll
    for (int r = 0; r < 4; r++) { v[r] = sA[r] * SCL; v[4 + r] = sB[r] * SCL; }
    if (key0 + 31 > q0w) {  // wave-uniform guard
      int thr = q0w + l15 - key0;
#pragma unroll
      for (int r = 0; r < 4; r++) {
        int k4 = g * 4 + r;
        if (k4 > thr) v[r] = -1e30f;
        if (k4 + 16 > thr) v[4 + r] = -1e30f;
      }
    }
    float mx = fmaxf(fmaxf(fmaxf(v[0], v[1]), fmaxf(v[2], v[3])),
                     fmaxf(fmaxf(v[4], v[5]), fmaxf(v[6], v[7])));
    mx = fmaxf(mx, __shfl_xor(mx, 16));
    mx = fmaxf(mx, __shfl_xor(mx, 32));
    float mnew = fmaxf(m, mx);
    float corr = fast_exp2(m - mnew);
    float p[8], sum = 0.0f;
#pragma unroll
    for (int i = 0; i < 8; i++) { p[i] = fast_exp2(v[i] - mnew); sum += p[i]; }
    sum += __shfl_xor(sum, 16);
    sum += __shfl_xor(sum, 32);
    l = l * corr + sum;
    m = mnew;
    o0 *= corr; o1 *= corr; o2 *= corr; o3 *= corr;
    bf16x4 pkA = {(__bf16)p[0], (__bf16)p[1], (__bf16)p[2], (__bf16)p[3]};
    bf16x4 pkB = {(__bf16)p[4], (__bf16)p[5], (__bf16)p[6], (__bf16)p[7]};
    o0 = mfma16(va0, pkA, o0); o0 = mfma16(vb0, pkB, o0);
    o1 = mfma16(va1, pkA, o1); o1 = mfma16(vb1, pkB, o1);
    o2 = mfma16(va2, pkA, o2); o2 = mfma16(vb2, pkB, o2);
    o3 = mfma16(va3, pkA, o3); o3 = mfma16(vb3, pkB, o3);

    __syncthreads();  // drains vmcnt(0): staged K(kt+1) ready; V regs done
    cur ^= 1;
  }

  float invl = 1.0f / l;
  __bf16* outp = attn_out + (size_t)(b * T_ + q0w + l15) * D_ + h * HD + g * 4;
  bf16x4 s0 = {(__bf16)(o0[0] * invl), (__bf16)(o0[1] * invl), (__bf16)(o0[2] * invl), (__bf16)(o0[3] * invl)};
  bf16x4 s1 = {(__bf16)(o1[0] * invl), (__bf16)(o1[1] * invl), (__bf16)(o1[2] * invl), (__bf16)(o1[3] * invl)};
  bf16x4 s2 = {(__bf16)(o2[0] * invl), (__bf16)(o2[1] * invl), (__bf16)(o2[2] * invl), (__bf16)(o2[3] * invl)};
  bf16x4 s3 = {(__bf16)(o3[0] * invl), (__bf16)(o3[1] * invl), (__bf16)(o3[2] * invl), (__bf16)(o3[3] * invl)};
  *(bf16x4*)(outp) = s0;
  *(bf16x4*)(outp + 16) = s1;
  *(bf16x4*)(outp + 32) = s2;
  *(bf16x4*)(outp + 48) = s3;
}

extern "C" void kernel_launch(void* const* d_in, const int* in_sizes, int n_in,
                              void* d_out, int out_size, void* d_ws, size_t ws_size,
                              hipStream_t stream) {
  (void)in_sizes; (void)n_in; (void)out_size; (void)ws_size;
  const float* x = (const float*)d_in[0];
  const float* W_attn = (const float*)d_in[1];
  const float* b_attn = (const float*)d_in[2];
  const float* W_proj = (const float*)d_in[3];
  const float* b_proj = (const float*)d_in[4];

  char* ws = (char*)d_ws;
  __bf16* xb  = (__bf16*)(ws + 0);          // 8192*768*2        = 12,582,912
  __bf16* WaT = (__bf16*)(ws + 12582912);   // 2304*768*2        =  3,538,944
  __bf16* WpT = (__bf16*)(ws + 16121856);   // 768*768*2         =  1,179,648
  __bf16* qkv = (__bf16*)(ws + 17301504);   // 8192*2304*2       = 37,748,736
  __bf16* VTb = (__bf16*)(ws + 55050240);   // 96*64*1024*2      = 12,582,912
  __bf16* att = (__bf16*)(ws + 67633152);   // 8192*768*2        = 12,582,912

  xconv_kernel<<<dim3(3072), 256, 0, stream>>>(x, xb, 786432);
  wtrans_kernel<<<dim3(72, 24), 256, 0, stream>>>(W_attn, WaT, 768, 2304);
  wtrans_kernel<<<dim3(24, 24), 256, 0, stream>>>(W_proj, WpT, 768, 768);
  gemm_kernel<0><<<dim3(18, 64), 256, 0, stream>>>(xb, WaT, b_attn, qkv, 8192, 2304, 768);
  vtrepack_kernel<<<dim3(16, 96), 256, 0, stream>>>(qkv, VTb);
  attn_kernel<<<dim3(96, 16), 256, 0, stream>>>(qkv, VTb, att);
  gemm_kernel<1><<<dim3(6, 64), 256, 0, stream>>>(att, WpT, b_proj, d_out, 8192, 768, 768);
}

// Round 9
// 120.462 us; speedup vs baseline: 1.7898x; 1.6221x over previous
//
#include <hip/hip_runtime.h>
#include <hip/hip_bf16.h>

// GPT2 attention: B=8, T=1024, D=768, H=12, hd=64. fp32 in/out, bf16 MFMA compute.
#define B_ 8
#define T_ 1024
#define D_ 768
#define NH 12
#define HD 64

typedef __bf16 bf16x8 __attribute__((ext_vector_type(8)));
typedef __bf16 bf16x4 __attribute__((ext_vector_type(4)));
typedef float f32x4 __attribute__((ext_vector_type(4)));
typedef short s16x4 __attribute__((ext_vector_type(4)));

__device__ __forceinline__ float fast_exp2(float x) {
  return __builtin_amdgcn_exp2f(x);
}

__device__ __forceinline__ f32x4 mfma32(bf16x8 a, bf16x8 b, f32x4 c) {
  return __builtin_amdgcn_mfma_f32_16x16x32_bf16(a, b, c, 0, 0, 0);
}

__device__ __forceinline__ f32x4 mfma16(bf16x4 a, bf16x4 b, f32x4 c) {
  union U { bf16x4 h; s16x4 s; };
  U ua; ua.h = a;
  U ub; ub.h = b;
  return __builtin_amdgcn_mfma_f32_16x16x16bf16_1k(ua.s, ub.s, c, 0, 0, 0);
}

// async global->LDS, 16B per lane; LDS dest is wave-uniform base + lane*16
__device__ __forceinline__ void gload_lds16(const void* g, void* l) {
  __builtin_amdgcn_global_load_lds((const __attribute__((address_space(1))) unsigned int*)g,
                                   (__attribute__((address_space(3))) unsigned int*)l, 16, 0, 0);
}

// ---------------- x (fp32) -> bf16 ----------------
__global__ void xconv_kernel(const float* __restrict__ x, __bf16* __restrict__ xb, int n8) {
  int i = blockIdx.x * 256 + threadIdx.x;
  if (i >= n8) return;
  const float4* xf = (const float4*)x;
  float4 a = xf[i * 2], b = xf[i * 2 + 1];
  bf16x8 v;
  v[0] = (__bf16)a.x; v[1] = (__bf16)a.y; v[2] = (__bf16)a.z; v[3] = (__bf16)a.w;
  v[4] = (__bf16)b.x; v[5] = (__bf16)b.y; v[6] = (__bf16)b.z; v[7] = (__bf16)b.w;
  *(bf16x8*)&xb[(size_t)i * 8] = v;
}

// ---------------- W (K x N fp32) -> WT (N x K bf16) ----------------
__global__ void wtrans_kernel(const float* __restrict__ W, __bf16* __restrict__ WT, int K, int N) {
  __shared__ float tile[32][33];
  int t = threadIdx.x, col = t & 31, r0 = t >> 5;
  int n0 = blockIdx.x * 32, k0 = blockIdx.y * 32;
#pragma unroll
  for (int p = 0; p < 4; p++) {
    int r = r0 + p * 8;
    tile[r][col] = W[(size_t)(k0 + r) * N + n0 + col];
  }
  __syncthreads();
#pragma unroll
  for (int p = 0; p < 4; p++) {
    int r = r0 + p * 8;
    WT[(size_t)(n0 + r) * K + k0 + col] = (__bf16)tile[col][r];
  }
}

// ---------------- GEMM: C(MxN) = A(MxK) * BT(NxK)^T + bias ----------------
template <int EPI>
__global__ __launch_bounds__(256) void gemm_kernel(const __bf16* __restrict__ A,
                                                   const __bf16* __restrict__ BT,
                                                   const float* __restrict__ bias,
                                                   void* __restrict__ Cout,
                                                   int M, int N, int K) {
  __shared__ __align__(16) __bf16 Asm[128][72];
  __shared__ __align__(16) __bf16 Bsm[128][72];
  int tid = threadIdx.x;
  int wave = tid >> 6, lane = tid & 63, g = lane >> 4, l15 = lane & 15;
  int wr = wave >> 1, wc = wave & 1;
  int m0 = blockIdx.y * 128, n0 = blockIdx.x * 128;
  int srow = tid >> 3, sk8 = tid & 7;
  const __bf16* Ag = A + (size_t)(m0 + srow) * K + sk8 * 8;
  const __bf16* Bg = BT + (size_t)(n0 + srow) * K + sk8 * 8;

  f32x4 zz = {0.0f, 0.0f, 0.0f, 0.0f};
  f32x4 acc[4][4];
#pragma unroll
  for (int m = 0; m < 4; m++)
#pragma unroll
    for (int n = 0; n < 4; n++) acc[m][n] = zz;

  int nk = K >> 6;
  bf16x8 Av[4], Bv[4];
#pragma unroll
  for (int p = 0; p < 4; p++) {
    Av[p] = *(const bf16x8*)(Ag + (size_t)p * 32 * K);
    Bv[p] = *(const bf16x8*)(Bg + (size_t)p * 32 * K);
  }
  for (int kt = 0; kt < nk; kt++) {
    __syncthreads();
#pragma unroll
    for (int p = 0; p < 4; p++) {
      *(bf16x8*)&Asm[srow + p * 32][sk8 * 8] = Av[p];
      *(bf16x8*)&Bsm[srow + p * 32][sk8 * 8] = Bv[p];
    }
    __syncthreads();
    if (kt + 1 < nk) {
#pragma unroll
      for (int p = 0; p < 4; p++) {
        Av[p] = *(const bf16x8*)(Ag + (kt + 1) * 64 + (size_t)p * 32 * K);
        Bv[p] = *(const bf16x8*)(Bg + (kt + 1) * 64 + (size_t)p * 32 * K);
      }
    }
#pragma unroll
    for (int ks = 0; ks < 2; ks++) {
      bf16x8 af[4], bfr[4];
#pragma unroll
      for (int m = 0; m < 4; m++) af[m] = *(const bf16x8*)&Asm[wr * 64 + m * 16 + l15][ks * 32 + g * 8];
#pragma unroll
      for (int n = 0; n < 4; n++) bfr[n] = *(const bf16x8*)&Bsm[wc * 64 + n * 16 + l15][ks * 32 + g * 8];
#pragma unroll
      for (int m = 0; m < 4; m++)
#pragma unroll
        for (int n = 0; n < 4; n++)
          acc[m][n] = __builtin_amdgcn_mfma_f32_16x16x32_bf16(af[m], bfr[n], acc[m][n], 0, 0, 0);
    }
  }
#pragma unroll
  for (int n = 0; n < 4; n++) {
    int gcol = n0 + wc * 64 + n * 16 + l15;
    float bv = bias[gcol];
#pragma unroll
    for (int m = 0; m < 4; m++) {
      int grow0 = m0 + wr * 64 + m * 16 + g * 4;
#pragma unroll
      for (int r = 0; r < 4; r++) {
        float v = acc[m][n][r] + bv;
        if (EPI == 0)
          ((__bf16*)Cout)[(size_t)(grow0 + r) * N + gcol] = (__bf16)v;
        else
          ((float*)Cout)[(size_t)(grow0 + r) * N + gcol] = v;
      }
    }
  }
}

// ---------------- V from qkv -> VT [bh][d][t] bf16 ----------------
__global__ void vtrepack_kernel(const __bf16* __restrict__ qkv, __bf16* __restrict__ VT) {
  __shared__ __align__(16) __bf16 tl[64][72];
  int bh = blockIdx.y;
  int b = bh / NH, h = bh % NH;
  int t0 = blockIdx.x * 64;
  int tid = threadIdx.x;
  int tr = tid >> 3, d8 = tid & 7;
#pragma unroll
  for (int p = 0; p < 2; p++) {
    int trow = tr + p * 32;
    bf16x8 v = *(const bf16x8*)&qkv[(size_t)(b * T_ + t0 + trow) * (3 * D_) + 2 * D_ + h * HD + d8 * 8];
#pragma unroll
    for (int e = 0; e < 8; e++) tl[d8 * 8 + e][trow] = v[e];
  }
  __syncthreads();
  int t8 = tid & 7;
#pragma unroll
  for (int p = 0; p < 2; p++) {
    int d = (tid >> 3) + p * 32;
    *(bf16x8*)&VT[((size_t)bh * HD + d) * T_ + t0 + t8 * 8] = *(const bf16x8*)&tl[d][t8 * 8];
  }
}

// ---------------- causal flash attention ----------------
// Block = (bh, 64 q-rows), 4 waves x 16 q-rows. KVBLK=64: K[64key][64d] AND
// V[64d][64key] staged in LDS (double-buffered, 32KB) via global_load_lds.
// XOR-swizzle (T2, both-sides per rule #21): staging pre-permutes the SOURCE
// chunk (c = (tid&7)^((tid>>3)&7)) so linear DMA writes land swizzled; reads
// apply chunk^(row&7). Kills r8's 5M 16-way conflicts (128B-row case, G4).
// Staggered K-tile start s0=(bh+qb)%nkt (online softmax is order-independent)
// de-hotspots L2: co-XCD blocks of a head no longer read identical lines in
// lockstep. One barrier per 64 keys; staging hides under the compute phase.
#define SCL 0.1803368801111204f  // 0.125 * log2(e)

__global__ __launch_bounds__(256, 4) void attn_kernel(const __bf16* __restrict__ qkv,
                                                      const __bf16* __restrict__ VT,
                                                      __bf16* __restrict__ attn_out) {
  __shared__ __align__(16) __bf16 sm[2][2][4096];  // [buf][0=K,1=V][64x64]
  int tid = threadIdx.x;
  int wave = tid >> 6, lane = tid & 63, g = lane >> 4, l15 = lane & 15;
  int bh = blockIdx.x;
  int b = bh / NH, h = bh % NH;
  int qb = 15 - blockIdx.y;  // heavy first
  int q0w = qb * 64 + wave * 16;
  int nkt = qb + 1;
  int s0 = (bh + qb) % nkt;

  // staging source: row kr = tid>>3 (+32 for round 1), pre-permuted chunk cc
  int kr = tid >> 3, cc = (tid & 7) ^ ((tid >> 3) & 7);
  const __bf16* Kst = qkv + (size_t)(b * T_ + kr) * (3 * D_) + D_ + h * HD + cc * 8;
  const __bf16* Vst = VT + ((size_t)bh * HD + kr) * T_ + cc * 8;
  __bf16* ldsK0 = &sm[0][0][wave * 512];  // wave-uniform DMA bases
  __bf16* ldsV0 = &sm[0][1][wave * 512];
  __bf16* ldsK1 = &sm[1][0][wave * 512];
  __bf16* ldsV1 = &sm[1][1][wave * 512];

  auto stage = [&](int t, int bf) {
    size_t ko = (size_t)(t * 64) * (3 * D_);
    int vo = t * 64;
    __bf16* lk = bf ? ldsK1 : ldsK0;
    __bf16* lv = bf ? ldsV1 : ldsV0;
    gload_lds16(Kst + ko, lk);
    gload_lds16(Kst + ko + (size_t)32 * (3 * D_), lk + 2048);
    gload_lds16(Vst + vo, lv);
    gload_lds16(Vst + vo + 32 * T_, lv + 2048);
  };

  // Q fragments (B-operand: col=q=l15, k=d)
  const __bf16* Qp = qkv + (size_t)(b * T_ + q0w + l15) * (3 * D_) + h * HD;
  bf16x8 qlo = *(const bf16x8*)(Qp + g * 8);
  bf16x8 qhi = *(const bf16x8*)(Qp + 32 + g * 8);

  f32x4 zz = {0.0f, 0.0f, 0.0f, 0.0f};
  f32x4 o0 = zz, o1 = zz, o2 = zz, o3 = zz;
  float m = -1e30f, l = 0.0f;
  int sw = l15 & 7;
  int clo = (g ^ sw) * 8;          // K lo-half chunk, swizzled (elements)
  int chi = ((4 + g) ^ sw) * 8;    // K hi-half chunk

  stage(s0, 0);
  __syncthreads();

  int cur = 0;
  for (int i = 0; i < nkt; i++) {
    int kt = s0 + i;
    if (kt >= nkt) kt -= nkt;
    if (i + 1 < nkt) stage(kt + 1 == nkt ? 0 : kt + 1, cur ^ 1);

    const __bf16* Kb = &sm[cur][0][0];
    f32x4 s[4];
#pragma unroll
    for (int kg = 0; kg < 4; kg++) {
      int rb = (kg * 16 + l15) * 64;
      bf16x8 kf = *(const bf16x8*)(Kb + rb + clo);
      bf16x8 kh = *(const bf16x8*)(Kb + rb + chi);
      s[kg] = mfma32(kf, qlo, zz);
      s[kg] = mfma32(kh, qhi, s[kg]);
    }

    float v[16];
#pragma unroll
    for (int kg = 0; kg < 4; kg++)
#pragma unroll
      for (int r = 0; r < 4; r++) v[kg * 4 + r] = s[kg][r] * SCL;
    if (kt == qb) {
      int thr = wave * 16 + l15;
#pragma unroll
      for (int kg = 0; kg < 4; kg++)
#pragma unroll
        for (int r = 0; r < 4; r++)
          if (kg * 16 + g * 4 + r > thr) v[kg * 4 + r] = -1e30f;
    }
    float m0a = fmaxf(fmaxf(v[0], v[1]), fmaxf(v[2], v[3]));
    float m1a = fmaxf(fmaxf(v[4], v[5]), fmaxf(v[6], v[7]));
    float m2a = fmaxf(fmaxf(v[8], v[9]), fmaxf(v[10], v[11]));
    float m3a = fmaxf(fmaxf(v[12], v[13]), fmaxf(v[14], v[15]));
    float mx = fmaxf(fmaxf(m0a, m1a), fmaxf(m2a, m3a));
    mx = fmaxf(mx, __shfl_xor(mx, 16));
    mx = fmaxf(mx, __shfl_xor(mx, 32));
    float mnew = fmaxf(m, mx);
    float corr = fast_exp2(m - mnew);
    float p[16], sum = 0.0f;
#pragma unroll
    for (int i2 = 0; i2 < 16; i2++) { p[i2] = fast_exp2(v[i2] - mnew); sum += p[i2]; }
    sum += __shfl_xor(sum, 16);
    sum += __shfl_xor(sum, 32);
    l = l * corr + sum;
    m = mnew;
    o0 *= corr; o1 *= corr; o2 *= corr; o3 *= corr;
    bf16x4 pk[4];
#pragma unroll
    for (int kg = 0; kg < 4; kg++) {
      pk[kg][0] = (__bf16)p[kg * 4 + 0];
      pk[kg][1] = (__bf16)p[kg * 4 + 1];
      pk[kg][2] = (__bf16)p[kg * 4 + 2];
      pk[kg][3] = (__bf16)p[kg * 4 + 3];
    }

    const __bf16* Vb = &sm[cur][1][0];
    int vhalf = (g & 1) * 4;
    int vc = g >> 1;
#pragma unroll
    for (int dq = 0; dq < 4; dq++) {
      int drow = (dq * 16 + l15) * 64;
#pragma unroll
      for (int ks = 0; ks < 4; ks++) {
        bf16x4 vf = *(const bf16x4*)(Vb + drow + ((ks * 2 + vc) ^ sw) * 8 + vhalf);
        f32x4* op = (dq == 0) ? &o0 : (dq == 1) ? &o1 : (dq == 2) ? &o2 : &o3;
        *op = mfma16(vf, pk[ks], *op);
      }
    }

    __syncthreads();
    cur ^= 1;
  }

  float invl = 1.0f / l;
  __bf16* outp = attn_out + (size_t)(b * T_ + q0w + l15) * D_ + h * HD + g * 4;
  bf16x4 t0 = {(__bf16)(o0[0] * invl), (__bf16)(o0[1] * invl), (__bf16)(o0[2] * invl), (__bf16)(o0[3] * invl)};
  bf16x4 t1 = {(__bf16)(o1[0] * invl), (__bf16)(o1[1] * invl), (__bf16)(o1[2] * invl), (__bf16)(o1[3] * invl)};
  bf16x4 t2 = {(__bf16)(o2[0] * invl), (__bf16)(o2[1] * invl), (__bf16)(o2[2] * invl), (__bf16)(o2[3] * invl)};
  bf16x4 t3 = {(__bf16)(o3[0] * invl), (__bf16)(o3[1] * invl), (__bf16)(o3[2] * invl), (__bf16)(o3[3] * invl)};
  *(bf16x4*)(outp) = t0;
  *(bf16x4*)(outp + 16) = t1;
  *(bf16x4*)(outp + 32) = t2;
  *(bf16x4*)(outp + 48) = t3;
}

extern "C" void kernel_launch(void* const* d_in, const int* in_sizes, int n_in,
                              void* d_out, int out_size, void* d_ws, size_t ws_size,
                              hipStream_t stream) {
  (void)in_sizes; (void)n_in; (void)out_size; (void)ws_size;
  const float* x = (const float*)d_in[0];
  const float* W_attn = (const float*)d_in[1];
  const float* b_attn = (const float*)d_in[2];
  const float* W_proj = (const float*)d_in[3];
  const float* b_proj = (const float*)d_in[4];

  char* ws = (char*)d_ws;
  __bf16* xb  = (__bf16*)(ws + 0);          // 8192*768*2        = 12,582,912
  __bf16* WaT = (__bf16*)(ws + 12582912);   // 2304*768*2        =  3,538,944
  __bf16* WpT = (__bf16*)(ws + 16121856);   // 768*768*2         =  1,179,648
  __bf16* qkv = (__bf16*)(ws + 17301504);   // 8192*2304*2       = 37,748,736
  __bf16* VTb = (__bf16*)(ws + 55050240);   // 96*64*1024*2      = 12,582,912
  __bf16* att = (__bf16*)(ws + 67633152);   // 8192*768*2        = 12,582,912

  xconv_kernel<<<dim3(3072), 256, 0, stream>>>(x, xb, 786432);
  wtrans_kernel<<<dim3(72, 24), 256, 0, stream>>>(W_attn, WaT, 768, 2304);
  wtrans_kernel<<<dim3(24, 24), 256, 0, stream>>>(W_proj, WpT, 768, 768);
  gemm_kernel<0><<<dim3(18, 64), 256, 0, stream>>>(xb, WaT, b_attn, qkv, 8192, 2304, 768);
  vtrepack_kernel<<<dim3(16, 96), 256, 0, stream>>>(qkv, VTb);
  attn_kernel<<<dim3(96, 16), 256, 0, stream>>>(qkv, VTb, att);
  gemm_kernel<1><<<dim3(6, 64), 256, 0, stream>>>(att, WpT, b_proj, d_out, 8192, 768, 768);
}